// Round 11
// baseline (120.714 us; speedup 1.0000x reference)
//
#include <hip/hip_runtime.h>

// ============================================================================
// r11: r9 semantics (verified: directed pairs, rev-first interleave), with
// 8 triu ranks per thread (was 4). Halves wave count -> halves per-wave fixed
// costs (tri-inversion, i-atom hoist loads, loop/address setup) per byte.
// Loads/pair and store-insts/byte unchanged. r10's d_ws table REVERTED
// (rewriting d_ws each replay defeats per-XCD L2 replication of read-only
// inputs and serializes behind the pack dispatch).
//   E = 2P = 33,538,048 directed pairs; layout idx0|idx1|dist|diff*3|valid.
//   d even: (j,i), diff=c[j]-c[i];  d odd: (i,j), diff=c[i]-c[j].
// ============================================================================

namespace r11 {

constexpr int kM = 8;
constexpr int kN = 2048;
constexpr int kPPM = kN * (kN - 1) / 2;     // 2,096,128 triu pairs per molecule
constexpr int kP   = kPPM * kM;             // 16,769,024 triu pairs total
constexpr long long E = 2LL * kP;           // 33,538,048 directed pairs
constexpr int kRanks = 8;                   // ranks per thread; 8 | kPPM

typedef __attribute__((ext_vector_type(8))) unsigned short u16x8;

__device__ __forceinline__ unsigned short f2bf(float f) {
    unsigned int u = __float_as_uint(f);
    u += 0x7FFFu + ((u >> 16) & 1u);        // round-to-nearest-even
    return (unsigned short)(u >> 16);
}

__device__ __forceinline__ int row_off(int i) {
    return (i * (2 * kN - 1 - i)) >> 1;
}

__global__ __launch_bounds__(256)
void fp_r11(const int* __restrict__ species,
            const float* __restrict__ coords,
            const int* __restrict__ cutw,
            unsigned short* __restrict__ out)
{
#pragma clang fp contract(off)
    const int g = blockIdx.x * 256 + threadIdx.x;   // group of 8 triu ranks
    const int t0 = g * kRanks;
    if (t0 >= kP) return;

    const int m = t0 / kPPM;                // 8 | kPPM -> group never crosses mol
    const int r0 = t0 - m * kPPM;

    // invert triangular index (4095^2 = 16,769,025 exact in f32)
    const float s = (float)(16769025 - 8 * r0);
    int i = (int)floorf((4095.0f - sqrtf(s)) * 0.5f);
    i = min(max(i, 0), kN - 2);
    while (row_off(i) > r0) --i;
    while (row_off(i + 1) <= r0) ++i;
    int j = i + 1 + (r0 - row_off(i));

    // cutoff: robust decode (int32 / int64-low-word / float32)
    const int w0 = cutw[0];
    const float cutoff = (w0 > 0 && w0 < (1 << 20)) ? (float)w0 : __int_as_float(w0);

    const int base = m * kN;

    // hoisted i-atom state (reloaded only on row wrap)
    int a = base + i;
    float ax = coords[3 * a + 0], ay = coords[3 * a + 1], az = coords[3 * a + 2];
    int   sa = species[a];
    unsigned short ba = f2bf((float)a);

    u16x8 vi0[2], vi1[2], vd[2], vv[2], vf[6];
    unsigned short df[48];

#pragma unroll
    for (int k = 0; k < kRanks; ++k) {
        const int b = base + j;

        const float bx = coords[3 * b + 0], by = coords[3 * b + 1], bz = coords[3 * b + 2];
        const int   sb = species[b];

        const float dx = ax - bx;
        const float dy = ay - by;
        const float dz = az - bz;
        const float d2 = dx * dx + dy * dy + dz * dz;   // no FMA: match np exactly
        const float dist = sqrtf(d2);

        const bool dummy = (sa == -1) || (sb == -1);
        const bool valid = (dist <= cutoff) && !dummy;

        const unsigned short bb = f2bf((float)b);
        const unsigned short bd = valid ? f2bf(dist) : (unsigned short)0;
        const unsigned short bv = valid ? (unsigned short)0x3F80 : (unsigned short)0;
        const unsigned short fx = valid ? f2bf(dx) : (unsigned short)0;   // fwd (i,j)
        const unsigned short fy = valid ? f2bf(dy) : (unsigned short)0;
        const unsigned short fz = valid ? f2bf(dz) : (unsigned short)0;
        const unsigned short gx = valid ? (unsigned short)(fx ^ 0x8000) : (unsigned short)0;
        const unsigned short gy = valid ? (unsigned short)(fy ^ 0x8000) : (unsigned short)0;
        const unsigned short gz = valid ? (unsigned short)(fz ^ 0x8000) : (unsigned short)0;

        // REV first (slot 2k): (j,i), diff = -(fwd); FWD second (slot 2k+1)
        const int s0 = 2 * k, s1 = 2 * k + 1;     // compile-time under unroll
        vi0[s0 >> 3][s0 & 7] = bb;  vi0[s1 >> 3][s1 & 7] = ba;
        vi1[s0 >> 3][s0 & 7] = ba;  vi1[s1 >> 3][s1 & 7] = bb;
        vd [s0 >> 3][s0 & 7] = bd;  vd [s1 >> 3][s1 & 7] = bd;
        vv [s0 >> 3][s0 & 7] = bv;  vv [s1 >> 3][s1 & 7] = bv;
        df[6 * k + 0] = gx;  df[6 * k + 1] = gy;  df[6 * k + 2] = gz;
        df[6 * k + 3] = fx;  df[6 * k + 4] = fy;  df[6 * k + 5] = fz;

        // advance; reload hoisted i-state on row wrap
        ++j;
        if (j == kN) {
            ++i; j = i + 1;
            if (k < kRanks - 1) {
                a = base + i;
                ax = coords[3 * a + 0]; ay = coords[3 * a + 1]; az = coords[3 * a + 2];
                sa = species[a];
                ba = f2bf((float)a);
            }
        }
    }

#pragma unroll
    for (int v = 0; v < 6; ++v)
#pragma unroll
        for (int e = 0; e < 8; ++e)
            vf[v][e] = df[8 * v + e];

    // 16B-aligned plain vector stores; 2 per scalar region, 6 for diff
    u16x8* o;
    o = (u16x8*)(out)         + 2 * g;  o[0] = vi0[0];  o[1] = vi0[1];   // idx0
    o = (u16x8*)(out + E)     + 2 * g;  o[0] = vi1[0];  o[1] = vi1[1];   // idx1
    o = (u16x8*)(out + 2 * E) + 2 * g;  o[0] = vd[0];   o[1] = vd[1];    // dist
    o = (u16x8*)(out + 3 * E) + 6 * g;                                   // diff
#pragma unroll
    for (int v = 0; v < 6; ++v) o[v] = vf[v];
    o = (u16x8*)(out + 6 * E) + 2 * g;  o[0] = vv[0];   o[1] = vv[1];    // valid
}

} // namespace r11

extern "C" void kernel_launch(void* const* d_in, const int* in_sizes, int n_in,
                              void* d_out, int out_size, void* d_ws, size_t ws_size,
                              hipStream_t stream) {
    using namespace r11;
    const int*   species = (const int*)d_in[0];
    const float* coords  = (const float*)d_in[1];
    const int*   cutoff  = (const int*)d_in[2];
    unsigned short* out  = (unsigned short*)d_out;

    const int groups = kP / kRanks;              // 2,096,128
    const int blocks = groups / 256;             // 8,188 exact
    fp_r11<<<blocks, 256, 0, stream>>>(species, coords, cutoff, out);
}

// Round 12
// 81.179 us; speedup vs baseline: 1.4870x; 1.4870x over previous
//
#include <hip/hip_runtime.h>

// ============================================================================
// r12 = exact revert to r9 (best: 82.5us, 5.69 TB/s effective write BW).
// History: r8 nt-stores -76%; r10 d_ws packed table -18% (per-replay table
// rewrite defeats XCD L2 replication + serializes behind pack dispatch);
// r11 8-ranks/thread -46% (VGPR state doubled, TLP halved). r9 structure =
// 4 triu ranks/thread, i-atom hoisted, plain 16B u16x8 stores.
//   E = 2P = 33,538,048 directed pairs; layout idx0|idx1|dist|diff*3|valid.
//   d even: (j,i), diff=c[j]-c[i];  d odd: (i,j), diff=c[i]-c[j].
// ============================================================================

namespace r12 {

constexpr int kM = 8;
constexpr int kN = 2048;
constexpr int kPPM = kN * (kN - 1) / 2;     // 2,096,128 triu pairs per molecule
constexpr int kP   = kPPM * kM;             // 16,769,024 triu pairs total
constexpr long long E = 2LL * kP;           // 33,538,048 directed pairs

typedef __attribute__((ext_vector_type(8))) unsigned short u16x8;

__device__ __forceinline__ unsigned short f2bf(float f) {
    unsigned int u = __float_as_uint(f);
    u += 0x7FFFu + ((u >> 16) & 1u);        // round-to-nearest-even
    return (unsigned short)(u >> 16);
}

__device__ __forceinline__ int row_off(int i) {
    return (i * (2 * kN - 1 - i)) >> 1;
}

__global__ __launch_bounds__(256)
void fp_r12(const int* __restrict__ species,
            const float* __restrict__ coords,
            const int* __restrict__ cutw,
            unsigned short* __restrict__ out)
{
#pragma clang fp contract(off)
    const int g = blockIdx.x * 256 + threadIdx.x;   // group of 4 triu ranks
    const int t0 = g * 4;
    if (t0 >= kP) return;

    const int m = t0 / kPPM;                // 4 | kPPM -> group never crosses mol
    const int r0 = t0 - m * kPPM;

    // invert triangular index (4095^2 = 16,769,025 exact in f32)
    const float s = (float)(16769025 - 8 * r0);
    int i = (int)floorf((4095.0f - sqrtf(s)) * 0.5f);
    i = min(max(i, 0), kN - 2);
    while (row_off(i) > r0) --i;
    while (row_off(i + 1) <= r0) ++i;
    int j = i + 1 + (r0 - row_off(i));

    // cutoff: robust decode (int32 / int64-low-word / float32)
    const int w0 = cutw[0];
    const float cutoff = (w0 > 0 && w0 < (1 << 20)) ? (float)w0 : __int_as_float(w0);

    const int base = m * kN;

    // hoisted i-atom state (reloaded only on row wrap, ~0.4% of iterations)
    int a = base + i;
    float ax = coords[3 * a + 0], ay = coords[3 * a + 1], az = coords[3 * a + 2];
    int   sa = species[a];
    unsigned short ba = f2bf((float)a);

    u16x8 vi0, vi1, vd, vv;
    u16x8 vf0, vf1, vf2;
    unsigned short df[24];

#pragma unroll
    for (int k = 0; k < 4; ++k) {
        const int b = base + j;

        const float bx = coords[3 * b + 0], by = coords[3 * b + 1], bz = coords[3 * b + 2];
        const int   sb = species[b];

        const float dx = ax - bx;
        const float dy = ay - by;
        const float dz = az - bz;
        const float d2 = dx * dx + dy * dy + dz * dz;   // no FMA: match np exactly
        const float dist = sqrtf(d2);

        const bool dummy = (sa == -1) || (sb == -1);
        const bool valid = (dist <= cutoff) && !dummy;

        const unsigned short bb = f2bf((float)b);
        const unsigned short bd = valid ? f2bf(dist) : (unsigned short)0;
        const unsigned short bv = valid ? (unsigned short)0x3F80 : (unsigned short)0;
        const unsigned short fx = valid ? f2bf(dx) : (unsigned short)0;   // fwd (i,j)
        const unsigned short fy = valid ? f2bf(dy) : (unsigned short)0;
        const unsigned short fz = valid ? f2bf(dz) : (unsigned short)0;
        const unsigned short gx = valid ? (unsigned short)(fx ^ 0x8000) : (unsigned short)0;
        const unsigned short gy = valid ? (unsigned short)(fy ^ 0x8000) : (unsigned short)0;
        const unsigned short gz = valid ? (unsigned short)(fz ^ 0x8000) : (unsigned short)0;

        // REV first (slot 2k): (j,i), diff = -(fwd); FWD second (slot 2k+1)
        vi0[2 * k]     = bb;  vi0[2 * k + 1] = ba;
        vi1[2 * k]     = ba;  vi1[2 * k + 1] = bb;
        vd[2 * k]      = bd;  vd[2 * k + 1]  = bd;
        vv[2 * k]      = bv;  vv[2 * k + 1]  = bv;
        df[6 * k + 0] = gx;  df[6 * k + 1] = gy;  df[6 * k + 2] = gz;
        df[6 * k + 3] = fx;  df[6 * k + 4] = fy;  df[6 * k + 5] = fz;

        // advance to next triu rank; reload hoisted i-state on row wrap
        ++j;
        if (j == kN) {
            ++i; j = i + 1;
            if (k < 3) {
                a = base + i;
                ax = coords[3 * a + 0]; ay = coords[3 * a + 1]; az = coords[3 * a + 2];
                sa = species[a];
                ba = f2bf((float)a);
            }
        }
    }

#pragma unroll
    for (int e = 0; e < 8; ++e) {
        vf0[e] = df[e];
        vf1[e] = df[8 + e];
        vf2[e] = df[16 + e];
    }

    // 16B-aligned PLAIN vector stores (L2 write-combine path)
    *((u16x8*)(out) + g)             = vi0;   // idx0
    *((u16x8*)(out + E) + g)         = vi1;   // idx1
    *((u16x8*)(out + 2 * E) + g)     = vd;    // dist
    u16x8* dfp = (u16x8*)(out + 3 * E) + 3 * g;   // diff
    dfp[0] = vf0; dfp[1] = vf1; dfp[2] = vf2;
    *((u16x8*)(out + 6 * E) + g)     = vv;    // valid
}

} // namespace r12

extern "C" void kernel_launch(void* const* d_in, const int* in_sizes, int n_in,
                              void* d_out, int out_size, void* d_ws, size_t ws_size,
                              hipStream_t stream) {
    using namespace r12;
    const int*   species = (const int*)d_in[0];
    const float* coords  = (const float*)d_in[1];
    const int*   cutoff  = (const int*)d_in[2];
    unsigned short* out  = (unsigned short*)d_out;

    const int groups = kP / 4;                   // 4,192,256
    const int blocks = groups / 256;             // 16,376 exact
    fp_r12<<<blocks, 256, 0, stream>>>(species, coords, cutoff, out);
}